// Round 11
// baseline (94.261 us; speedup 1.0000x reference)
//
#include <hip/hip_runtime.h>

// ROUND 11 = INSTRUMENTED DIAGNOSTIC.
// Both kernels run their compute 4x idempotently (REP loop) so each exceeds
// the harness's ~43us ws-poison fills and appears in rocprof top-5 WITH
// counters. Output remains exactly correct (each rep overwrites same values).
//   K1 kA_rep   : xpT[s][kd][i] = partial (inputs @ T)^T   x4
//   K2 pair_rep : fold splits in LDS fill, then pairwise exp2(-L1), R=4   x4
//
// inputs [512,1024] f32, T [1024,500] f32, out [512,100] f32.

#define BB 512
#define FF 1024
#define KK 100
#define KD 500
#define KDP 512
#define SPLITS 8
#define FN (FF / SPLITS)   // 128 f per split
#define STEPS (FN / 16)    // 8
#define LOG2E 1.4426950408889634f
#define REPS 4

// ---------------- K1: split-K GEMM tile, transposed store, x REPS ---------
// grid = 512 blocks (8 i x 8 kd x 8 splits), block 256, 2/CU.
__global__ __launch_bounds__(256, 2) void kA_rep(
    const float* __restrict__ in, const float* __restrict__ T,
    float* __restrict__ xpT)
{
    __shared__ __align__(16) float smem[2112];
    float (*Ads)[68] = (float(*)[68])smem;            // [16][68]
    float (*Bds)[64] = (float(*)[64])(smem + 1088);   // [16][64]

    const int b = blockIdx.x;
    const int t = threadIdx.x;
    const int i0  = (b & 7) * 64;
    const int kd0 = ((b >> 3) & 7) * 64;
    const int s   = b >> 6;                // 0..7
    const int tk  = t & 15;
    const int ti  = t >> 4;

    const int ia  = t >> 2;                // i row for A staging
    const int fqa = t & 3;                 // f-quad for A
    const int kb  = t & 63;                // kd lane for B
    const int frb = t >> 6;                // f-quad for B
    const int kbc = min(kd0 + kb, KD - 1);

    const float* inb = in + (size_t)(i0 + ia) * FF + s * FN;
    const float* Tb  = T + (size_t)(s * FN) * KD + kbc;

    for (int rep = 0; rep < REPS; ++rep) {
        float z;
        asm volatile("v_mov_b32 %0, 0" : "=v"(z));   // opaque zero: no cross-rep CSE
        float acc[4][4];
        #pragma unroll
        for (int r = 0; r < 4; ++r)
            #pragma unroll
            for (int c = 0; c < 4; ++c) acc[r][c] = z;

        float4 av = *(const float4*)&inb[fqa * 4];
        float bv0 = Tb[(size_t)(frb * 4 + 0) * KD];
        float bv1 = Tb[(size_t)(frb * 4 + 1) * KD];
        float bv2 = Tb[(size_t)(frb * 4 + 2) * KD];
        float bv3 = Tb[(size_t)(frb * 4 + 3) * KD];

        for (int step = 0; step < STEPS; ++step) {
            Ads[fqa * 4 + 0][ia] = av.x;
            Ads[fqa * 4 + 1][ia] = av.y;
            Ads[fqa * 4 + 2][ia] = av.z;
            Ads[fqa * 4 + 3][ia] = av.w;
            Bds[frb * 4 + 0][kb] = bv0;
            Bds[frb * 4 + 1][kb] = bv1;
            Bds[frb * 4 + 2][kb] = bv2;
            Bds[frb * 4 + 3][kb] = bv3;
            __syncthreads();

            if (step + 1 < STEPS) {        // prefetch next step under the FMAs
                const int fo = (step + 1) * 16;
                av  = *(const float4*)&inb[fo + fqa * 4];
                bv0 = Tb[(size_t)(fo + frb * 4 + 0) * KD];
                bv1 = Tb[(size_t)(fo + frb * 4 + 1) * KD];
                bv2 = Tb[(size_t)(fo + frb * 4 + 2) * KD];
                bv3 = Tb[(size_t)(fo + frb * 4 + 3) * KD];
            }

            #pragma unroll
            for (int f = 0; f < 16; ++f) {
                float4 a  = *(const float4*)&Ads[f][ti * 4];
                float4 bq = *(const float4*)&Bds[f][tk * 4];
                float ar[4] = {a.x, a.y, a.z, a.w};
                float br[4] = {bq.x, bq.y, bq.z, bq.w};
                #pragma unroll
                for (int r = 0; r < 4; ++r)
                    #pragma unroll
                    for (int c = 0; c < 4; ++c)
                        acc[r][c] = fmaf(ar[r], br[c], acc[r][c]);
            }
            __syncthreads();
        }

        // store every rep (idempotent) so no rep is dead code
        #pragma unroll
        for (int c = 0; c < 4; ++c) {
            float4 v = {acc[0][c], acc[1][c], acc[2][c], acc[3][c]};
            *(float4*)&xpT[((size_t)s * KDP + kd0 + tk * 4 + c) * BB + i0 + ti * 4] = v;
        }
    }
}

// ---------------- K2: fold + pairwise exp2(-L1), R=4, x REPS --------------
// grid (100 k, 2 i-halves), block 512 (8 waves). Wave w: j in [w*64,(w+1)*64).
__global__ __launch_bounds__(512) void pair_rep(
    const float* __restrict__ xpT, float* __restrict__ out)
{
    const int k = blockIdx.x;
    const int p = blockIdx.y;
    const int t = threadIdx.x;
    const int lane = t & 63;
    const int w    = t >> 6;

    __shared__ float xs[BB][8];     // 16 KiB
    __shared__ float ps[8][256];    // 8 KiB

    // fill: fold 8 split partials for row j=t, pre-scale by log2e. Coalesced.
    #pragma unroll
    for (int d = 0; d < 5; ++d) {
        float v = 0.f;
        #pragma unroll
        for (int s = 0; s < SPLITS; ++s)
            v += xpT[((size_t)s * KDP + k * 5 + d) * BB + t];
        xs[t][d] = LOG2E * v;
    }
    __syncthreads();

    float xi[4][5];
    #pragma unroll
    for (int r = 0; r < 4; ++r) {
        const int i = p * 256 + r * 64 + lane;
        #pragma unroll
        for (int d = 0; d < 5; ++d) xi[r][d] = xs[i][d];
    }

    for (int rep = 0; rep < REPS; ++rep) {
        float z;
        asm volatile("v_mov_b32 %0, 0" : "=v"(z));   // opaque zero per rep
        float acc[4] = {z, z, z, z};
        const int j0 = w << 6;
        #pragma unroll 2
        for (int jj = 0; jj < 64; ++jj) {
            const int j = j0 + jj;         // wave-uniform -> LDS broadcast
            float4 xj0 = *(const float4*)&xs[j][0];
            float  xj4 = xs[j][4];
            #pragma unroll
            for (int r = 0; r < 4; ++r) {
                float aa = (fabsf(xi[r][0] - xj0.x) + fabsf(xi[r][1] - xj0.y))
                         + (fabsf(xi[r][2] - xj0.z) + fabsf(xi[r][3] - xj0.w))
                         + fabsf(xi[r][4] - xj4);
                acc[r] += __builtin_amdgcn_exp2f(-aa);
            }
        }

        #pragma unroll
        for (int r = 0; r < 4; ++r) ps[w][r * 64 + lane] = acc[r];
        __syncthreads();

        if (t < 256) {
            float v = 0.f;
            #pragma unroll
            for (int q = 0; q < 8; ++q) v += ps[q][t];
            out[(size_t)(p * 256 + t) * KK + k] = v;   // idempotent across reps
        }
        __syncthreads();                   // protect ps before next rep
    }
}

// ---------------- last-resort fallback (ws too small) ----------------
__global__ __launch_bounds__(1024, 1) void mbd_fused(
    const float* __restrict__ in, const float* __restrict__ T, float* __restrict__ out)
{
    const int k = blockIdx.x;
    const int t = threadIdx.x;
    const int i = t & (BB - 1);
    const int h = t >> 9;

    __shared__ float xk[1024][8];

    float a0 = 0.f, a1 = 0.f, a2 = 0.f, a3 = 0.f, a4 = 0.f;
    const float4* inrow = (const float4*)(in + (size_t)i * FF + (size_t)h * 512);
    const float* Tk = T + 5 * k + (size_t)h * 512 * KD;

    for (int ff = 0; ff < 512; ff += 4) {
        float4 v = inrow[ff >> 2];
        const float* tp = Tk + (size_t)ff * KD;
        a0 = fmaf(v.x, tp[0], a0); a1 = fmaf(v.x, tp[1], a1); a2 = fmaf(v.x, tp[2], a2);
        a3 = fmaf(v.x, tp[3], a3); a4 = fmaf(v.x, tp[4], a4); tp += KD;
        a0 = fmaf(v.y, tp[0], a0); a1 = fmaf(v.y, tp[1], a1); a2 = fmaf(v.y, tp[2], a2);
        a3 = fmaf(v.y, tp[3], a3); a4 = fmaf(v.y, tp[4], a4); tp += KD;
        a0 = fmaf(v.z, tp[0], a0); a1 = fmaf(v.z, tp[1], a1); a2 = fmaf(v.z, tp[2], a2);
        a3 = fmaf(v.z, tp[3], a3); a4 = fmaf(v.z, tp[4], a4); tp += KD;
        a0 = fmaf(v.w, tp[0], a0); a1 = fmaf(v.w, tp[1], a1); a2 = fmaf(v.w, tp[2], a2);
        a3 = fmaf(v.w, tp[3], a3); a4 = fmaf(v.w, tp[4], a4);
    }
    xk[t][0] = a0; xk[t][1] = a1; xk[t][2] = a2; xk[t][3] = a3; xk[t][4] = a4;
    __syncthreads();
    if (t < BB) {
        xk[t][0] += xk[t + BB][0]; xk[t][1] += xk[t + BB][1]; xk[t][2] += xk[t + BB][2];
        xk[t][3] += xk[t + BB][3]; xk[t][4] += xk[t + BB][4];
    }
    __syncthreads();

    const int jg = t >> 9;
    const float4 xiv = *(const float4*)&xk[i][0];
    const float xi4 = xk[i][4];
    float s0 = 0.f;
    const int j0 = jg << 8;
    for (int jj = 0; jj < 256; ++jj) {
        const int j = j0 + jj;
        float4 xj = *(const float4*)&xk[j][0];
        float xj4 = xk[j][4];
        float aa = (fabsf(xiv.x - xj.x) + fabsf(xiv.y - xj.y))
                 + (fabsf(xiv.z - xj.z) + fabsf(xiv.w - xj.w)) + fabsf(xi4 - xj4);
        s0 += __builtin_amdgcn_exp2f(-1.4426950408889634f * aa);
    }
    xk[BB + i][jg] = s0;
    __syncthreads();
    if (t < BB)
        out[(size_t)t * KK + k] = xk[BB + t][0] + xk[BB + t][1];
}

// ---------------- launch ----------------
extern "C" void kernel_launch(void* const* d_in, const int* in_sizes, int n_in,
                              void* d_out, int out_size, void* d_ws, size_t ws_size,
                              hipStream_t stream) {
    const float* in = (const float*)d_in[0];   // [512, 1024]
    const float* T  = (const float*)d_in[1];   // [1024, 500]
    float* out = (float*)d_out;                // [512, 100]

    const size_t xpT_bytes = (size_t)SPLITS * KDP * BB * sizeof(float);  // 8 MiB

    if (ws_size < xpT_bytes) {
        mbd_fused<<<KK, 1024, 0, stream>>>(in, T, out);
        return;
    }

    float* xpT = (float*)d_ws;

    kA_rep<<<512, 256, 0, stream>>>(in, T, xpT);

    dim3 g2(KK, 2);                    // 200 blocks
    pair_rep<<<g2, 512, 0, stream>>>(xpT, out);
}

// Round 12
// 53.763 us; speedup vs baseline: 1.7533x; 1.7533x over previous
//
#include <hip/hip_runtime.h>

// MinibatchDiscrimination, round 12:
//   memset   : out = 0
//   K1 kA    : xpT[s][kd][i] = partial (inputs @ T)^T   (unchanged control)
//   K2 kB    : xT[kd][i] = log2e * sum_s xpT[s][kd][i]  (coalesced float4)
//   K3 pair8 : out[i,k] += sum_{j in 64-slice} exp2(-L1)   R=8 i-rows/thread,
//              800 blocks for occupancy, LDS wave-reduce + unsafeAtomicAdd.
//
// inputs [512,1024] f32, T [1024,500] f32, out [512,100] f32.

#define BB 512
#define FF 1024
#define KK 100
#define KD 500
#define KDP 512
#define SPLITS 8
#define FN (FF / SPLITS)   // 128 f per split
#define STEPS (FN / 16)    // 8
#define LOG2E 1.4426950408889634f

// ---------------- K1: split-K GEMM tile, transposed partial store ---------
// grid = 512 blocks (8 i x 8 kd x 8 splits), block 256, 2/CU. ~7-12us.
__global__ __launch_bounds__(256, 2) void kA(
    const float* __restrict__ in, const float* __restrict__ T,
    float* __restrict__ xpT)
{
    __shared__ __align__(16) float smem[2112];
    float (*Ads)[68] = (float(*)[68])smem;            // [16][68]
    float (*Bds)[64] = (float(*)[64])(smem + 1088);   // [16][64]

    const int b = blockIdx.x;
    const int t = threadIdx.x;
    const int i0  = (b & 7) * 64;
    const int kd0 = ((b >> 3) & 7) * 64;
    const int s   = b >> 6;                // 0..7
    const int tk  = t & 15;
    const int ti  = t >> 4;

    float acc[4][4];
    #pragma unroll
    for (int r = 0; r < 4; ++r)
        #pragma unroll
        for (int c = 0; c < 4; ++c) acc[r][c] = 0.f;

    const int ia  = t >> 2;                // i row for A staging
    const int fqa = t & 3;                 // f-quad for A
    const int kb  = t & 63;                // kd lane for B
    const int frb = t >> 6;                // f-quad for B
    const int kbc = min(kd0 + kb, KD - 1);

    const float* inb = in + (size_t)(i0 + ia) * FF + s * FN;
    const float* Tb  = T + (size_t)(s * FN) * KD + kbc;

    float4 av = *(const float4*)&inb[fqa * 4];
    float bv0 = Tb[(size_t)(frb * 4 + 0) * KD];
    float bv1 = Tb[(size_t)(frb * 4 + 1) * KD];
    float bv2 = Tb[(size_t)(frb * 4 + 2) * KD];
    float bv3 = Tb[(size_t)(frb * 4 + 3) * KD];

    for (int step = 0; step < STEPS; ++step) {
        Ads[fqa * 4 + 0][ia] = av.x;
        Ads[fqa * 4 + 1][ia] = av.y;
        Ads[fqa * 4 + 2][ia] = av.z;
        Ads[fqa * 4 + 3][ia] = av.w;
        Bds[frb * 4 + 0][kb] = bv0;
        Bds[frb * 4 + 1][kb] = bv1;
        Bds[frb * 4 + 2][kb] = bv2;
        Bds[frb * 4 + 3][kb] = bv3;
        __syncthreads();

        if (step + 1 < STEPS) {            // prefetch next step under the FMAs
            const int fo = (step + 1) * 16;
            av  = *(const float4*)&inb[fo + fqa * 4];
            bv0 = Tb[(size_t)(fo + frb * 4 + 0) * KD];
            bv1 = Tb[(size_t)(fo + frb * 4 + 1) * KD];
            bv2 = Tb[(size_t)(fo + frb * 4 + 2) * KD];
            bv3 = Tb[(size_t)(fo + frb * 4 + 3) * KD];
        }

        #pragma unroll
        for (int f = 0; f < 16; ++f) {
            float4 a  = *(const float4*)&Ads[f][ti * 4];
            float4 bq = *(const float4*)&Bds[f][tk * 4];
            float ar[4] = {a.x, a.y, a.z, a.w};
            float br[4] = {bq.x, bq.y, bq.z, bq.w};
            #pragma unroll
            for (int r = 0; r < 4; ++r)
                #pragma unroll
                for (int c = 0; c < 4; ++c)
                    acc[r][c] = fmaf(ar[r], br[c], acc[r][c]);
        }
        __syncthreads();
    }

    #pragma unroll
    for (int c = 0; c < 4; ++c) {
        float4 v = {acc[0][c], acc[1][c], acc[2][c], acc[3][c]};
        *(float4*)&xpT[((size_t)s * KDP + kd0 + tk * 4 + c) * BB + i0 + ti * 4] = v;
    }
}

// ---------------- K2: fold splits + scale, fully coalesced ---------------
__global__ __launch_bounds__(256) void kB(
    const float* __restrict__ xpT, float* __restrict__ xT)
{
    const int e = blockIdx.x * 256 + threadIdx.x;    // float4 idx < 65536
    const float4* p = (const float4*)xpT;
    float4 v = p[e];
    #pragma unroll
    for (int s = 1; s < SPLITS; ++s) {
        float4 w = p[(size_t)s * (KDP * BB / 4) + e];
        v.x += w.x; v.y += w.y; v.z += w.z; v.w += w.w;
    }
    v.x *= LOG2E; v.y *= LOG2E; v.z *= LOG2E; v.w *= LOG2E;
    ((float4*)xT)[e] = v;
}

// ---------------- K3: pairwise exp2(-L1), R=8 rows/thread, 800 blocks -----
// grid (100 k, 8 jp), block 256 (4 waves). Wave w: j in [jp*64+w*16, +16).
// Each thread: i = r*64+lane for r=0..7 (whole batch). 2 broadcast LDS reads
// per j feed 72 VALU + 8 exp. Wave partials LDS-reduced, then atomicAdd.
__global__ __launch_bounds__(256) void pair8(
    const float* __restrict__ xT, float* __restrict__ out)
{
    const int k  = blockIdx.x;
    const int jp = blockIdx.y;
    const int t  = threadIdx.x;
    const int lane = t & 63;
    const int w    = t >> 6;

    __shared__ float xs4[BB][4];   // d0..d3, 16B rows  (8 KiB)
    __shared__ float xs1[BB];      // d4               (2 KiB)
    __shared__ float ps[4][BB];    // wave partials    (8 KiB)

    // fill all 512 rows from xT (coalesced per-d row reads)
    #pragma unroll
    for (int q = 0; q < 2; ++q) {
        const int j = t + q * 256;
        float d0 = xT[(size_t)(k * 5 + 0) * BB + j];
        float d1 = xT[(size_t)(k * 5 + 1) * BB + j];
        float d2 = xT[(size_t)(k * 5 + 2) * BB + j];
        float d3 = xT[(size_t)(k * 5 + 3) * BB + j];
        float d4 = xT[(size_t)(k * 5 + 4) * BB + j];
        float4 v = {d0, d1, d2, d3};
        *(float4*)&xs4[j][0] = v;
        xs1[j] = d4;
    }
    __syncthreads();

    // register-resident xi: 8 rows per thread (one-time LDS reads)
    float xi[8][5];
    #pragma unroll
    for (int r = 0; r < 8; ++r) {
        const int i = r * 64 + lane;
        float4 v = *(const float4*)&xs4[i][0];
        xi[r][0] = v.x; xi[r][1] = v.y; xi[r][2] = v.z; xi[r][3] = v.w;
        xi[r][4] = xs1[i];
    }

    float acc[8] = {0.f, 0.f, 0.f, 0.f, 0.f, 0.f, 0.f, 0.f};
    const int j0 = jp * 64 + w * 16;
    #pragma unroll 2
    for (int jj = 0; jj < 16; ++jj) {
        const int j = j0 + jj;             // wave-uniform -> LDS broadcast
        float4 xj = *(const float4*)&xs4[j][0];
        float  x4 = xs1[j];
        #pragma unroll
        for (int r = 0; r < 8; ++r) {
            float aa = (fabsf(xi[r][0] - xj.x) + fabsf(xi[r][1] - xj.y))
                     + (fabsf(xi[r][2] - xj.z) + fabsf(xi[r][3] - xj.w))
                     + fabsf(xi[r][4] - x4);
            acc[r] += __builtin_amdgcn_exp2f(-aa);
        }
    }

    #pragma unroll
    for (int r = 0; r < 8; ++r) ps[w][r * 64 + lane] = acc[r];
    __syncthreads();

    #pragma unroll
    for (int q = 0; q < 2; ++q) {
        const int i = t + q * 256;
        const float v = (ps[0][i] + ps[1][i]) + (ps[2][i] + ps[3][i]);
        unsafeAtomicAdd(&out[(size_t)i * KK + k], v);
    }
}

// ---------------- last-resort fallback (ws too small) ----------------
__global__ __launch_bounds__(1024, 1) void mbd_fused(
    const float* __restrict__ in, const float* __restrict__ T, float* __restrict__ out)
{
    const int k = blockIdx.x;
    const int t = threadIdx.x;
    const int i = t & (BB - 1);
    const int h = t >> 9;

    __shared__ float xk[1024][8];

    float a0 = 0.f, a1 = 0.f, a2 = 0.f, a3 = 0.f, a4 = 0.f;
    const float4* inrow = (const float4*)(in + (size_t)i * FF + (size_t)h * 512);
    const float* Tk = T + 5 * k + (size_t)h * 512 * KD;

    for (int ff = 0; ff < 512; ff += 4) {
        float4 v = inrow[ff >> 2];
        const float* tp = Tk + (size_t)ff * KD;
        a0 = fmaf(v.x, tp[0], a0); a1 = fmaf(v.x, tp[1], a1); a2 = fmaf(v.x, tp[2], a2);
        a3 = fmaf(v.x, tp[3], a3); a4 = fmaf(v.x, tp[4], a4); tp += KD;
        a0 = fmaf(v.y, tp[0], a0); a1 = fmaf(v.y, tp[1], a1); a2 = fmaf(v.y, tp[2], a2);
        a3 = fmaf(v.y, tp[3], a3); a4 = fmaf(v.y, tp[4], a4); tp += KD;
        a0 = fmaf(v.z, tp[0], a0); a1 = fmaf(v.z, tp[1], a1); a2 = fmaf(v.z, tp[2], a2);
        a3 = fmaf(v.z, tp[3], a3); a4 = fmaf(v.z, tp[4], a4); tp += KD;
        a0 = fmaf(v.w, tp[0], a0); a1 = fmaf(v.w, tp[1], a1); a2 = fmaf(v.w, tp[2], a2);
        a3 = fmaf(v.w, tp[3], a3); a4 = fmaf(v.w, tp[4], a4);
    }
    xk[t][0] = a0; xk[t][1] = a1; xk[t][2] = a2; xk[t][3] = a3; xk[t][4] = a4;
    __syncthreads();
    if (t < BB) {
        xk[t][0] += xk[t + BB][0]; xk[t][1] += xk[t + BB][1]; xk[t][2] += xk[t + BB][2];
        xk[t][3] += xk[t + BB][3]; xk[t][4] += xk[t + BB][4];
    }
    __syncthreads();

    const int jg = t >> 9;
    const float4 xiv = *(const float4*)&xk[i][0];
    const float xi4 = xk[i][4];
    float s0 = 0.f;
    const int j0 = jg << 8;
    for (int jj = 0; jj < 256; ++jj) {
        const int j = j0 + jj;
        float4 xj = *(const float4*)&xk[j][0];
        float xj4 = xk[j][4];
        float aa = (fabsf(xiv.x - xj.x) + fabsf(xiv.y - xj.y))
                 + (fabsf(xiv.z - xj.z) + fabsf(xiv.w - xj.w)) + fabsf(xi4 - xj4);
        s0 += __builtin_amdgcn_exp2f(-1.4426950408889634f * aa);
    }
    xk[BB + i][jg] = s0;
    __syncthreads();
    if (t < BB)
        out[(size_t)t * KK + k] = xk[BB + t][0] + xk[BB + t][1];
}

// ---------------- launch ----------------
extern "C" void kernel_launch(void* const* d_in, const int* in_sizes, int n_in,
                              void* d_out, int out_size, void* d_ws, size_t ws_size,
                              hipStream_t stream) {
    const float* in = (const float*)d_in[0];   // [512, 1024]
    const float* T  = (const float*)d_in[1];   // [1024, 500]
    float* out = (float*)d_out;                // [512, 100]

    const size_t xpT_bytes = (size_t)SPLITS * KDP * BB * sizeof(float);  // 8 MiB
    const size_t xT_bytes  = (size_t)KDP * BB * sizeof(float);           // 1 MiB

    if (ws_size < xpT_bytes + xT_bytes) {
        mbd_fused<<<KK, 1024, 0, stream>>>(in, T, out);
        return;
    }

    float* xpT = (float*)d_ws;
    float* xT  = (float*)((char*)d_ws + xpT_bytes);

    hipMemsetAsync(out, 0, (size_t)BB * KK * sizeof(float), stream);

    kA<<<512, 256, 0, stream>>>(in, T, xpT);
    kB<<<256, 256, 0, stream>>>(xpT, xT);

    dim3 g3(KK, 8);                    // 800 blocks
    pair8<<<g3, 256, 0, stream>>>(xT, out);
}

// Round 13
// 37.607 us; speedup vs baseline: 2.5065x; 1.4296x over previous
//
#include <hip/hip_runtime.h>

// MinibatchDiscrimination, round 13:
//   K1 kA     : xpT[s][kd][i] = partial (inputs @ T)^T  (unchanged, ~8us)
//   K2 pair2k : fold 8 splits during LDS fill (2 k's per block, 10 floats/row),
//               then out[i,k] = sum_j exp2(-L1). Per j: 3 broadcast LDS reads
//               serve 2i x 2k pairs -> VALU-bound (84 VALU cyc vs 32 LDS cyc).
//
// inputs [512,1024] f32, T [1024,500] f32, out [512,100] f32.

#define BB 512
#define FF 1024
#define KK 100
#define KD 500
#define KDP 512
#define SPLITS 8
#define FN (FF / SPLITS)   // 128 f per split
#define STEPS (FN / 16)    // 8
#define LOG2E 1.4426950408889634f

// ---------------- K1: split-K GEMM tile, transposed partial store ---------
// grid = 512 blocks (8 i x 8 kd x 8 splits), block 256, 2/CU.
__global__ __launch_bounds__(256, 2) void kA(
    const float* __restrict__ in, const float* __restrict__ T,
    float* __restrict__ xpT)
{
    __shared__ __align__(16) float smem[2112];
    float (*Ads)[68] = (float(*)[68])smem;            // [16][68]
    float (*Bds)[64] = (float(*)[64])(smem + 1088);   // [16][64]

    const int b = blockIdx.x;
    const int t = threadIdx.x;
    const int i0  = (b & 7) * 64;
    const int kd0 = ((b >> 3) & 7) * 64;
    const int s   = b >> 6;                // 0..7
    const int tk  = t & 15;
    const int ti  = t >> 4;

    float acc[4][4];
    #pragma unroll
    for (int r = 0; r < 4; ++r)
        #pragma unroll
        for (int c = 0; c < 4; ++c) acc[r][c] = 0.f;

    const int ia  = t >> 2;                // i row for A staging
    const int fqa = t & 3;                 // f-quad for A
    const int kb  = t & 63;                // kd lane for B
    const int frb = t >> 6;                // f-quad for B
    const int kbc = min(kd0 + kb, KD - 1);

    const float* inb = in + (size_t)(i0 + ia) * FF + s * FN;
    const float* Tb  = T + (size_t)(s * FN) * KD + kbc;

    float4 av = *(const float4*)&inb[fqa * 4];
    float bv0 = Tb[(size_t)(frb * 4 + 0) * KD];
    float bv1 = Tb[(size_t)(frb * 4 + 1) * KD];
    float bv2 = Tb[(size_t)(frb * 4 + 2) * KD];
    float bv3 = Tb[(size_t)(frb * 4 + 3) * KD];

    for (int step = 0; step < STEPS; ++step) {
        Ads[fqa * 4 + 0][ia] = av.x;
        Ads[fqa * 4 + 1][ia] = av.y;
        Ads[fqa * 4 + 2][ia] = av.z;
        Ads[fqa * 4 + 3][ia] = av.w;
        Bds[frb * 4 + 0][kb] = bv0;
        Bds[frb * 4 + 1][kb] = bv1;
        Bds[frb * 4 + 2][kb] = bv2;
        Bds[frb * 4 + 3][kb] = bv3;
        __syncthreads();

        if (step + 1 < STEPS) {            // prefetch next step under the FMAs
            const int fo = (step + 1) * 16;
            av  = *(const float4*)&inb[fo + fqa * 4];
            bv0 = Tb[(size_t)(fo + frb * 4 + 0) * KD];
            bv1 = Tb[(size_t)(fo + frb * 4 + 1) * KD];
            bv2 = Tb[(size_t)(fo + frb * 4 + 2) * KD];
            bv3 = Tb[(size_t)(fo + frb * 4 + 3) * KD];
        }

        #pragma unroll
        for (int f = 0; f < 16; ++f) {
            float4 a  = *(const float4*)&Ads[f][ti * 4];
            float4 bq = *(const float4*)&Bds[f][tk * 4];
            float ar[4] = {a.x, a.y, a.z, a.w};
            float br[4] = {bq.x, bq.y, bq.z, bq.w};
            #pragma unroll
            for (int r = 0; r < 4; ++r)
                #pragma unroll
                for (int c = 0; c < 4; ++c)
                    acc[r][c] = fmaf(ar[r], br[c], acc[r][c]);
        }
        __syncthreads();
    }

    #pragma unroll
    for (int c = 0; c < 4; ++c) {
        float4 v = {acc[0][c], acc[1][c], acc[2][c], acc[3][c]};
        *(float4*)&xpT[((size_t)s * KDP + kd0 + tk * 4 + c) * BB + i0 + ti * 4] = v;
    }
}

// ---------------- K2: fold + pairwise exp2(-L1), 2 k's per block ----------
// grid (50 k-pairs, 4 i-quarters) = 200 blocks, block 512 (8 waves).
// Row j layout (12 floats): [k0d0..k0d3][k0d4,k1d0..k1d2][k1d3,k1d4,pad,pad]
// Wave w: j in [w*64,(w+1)*64). Thread: i = ip*128 + r*64 + lane, r=0..1.
__global__ __launch_bounds__(512) void pair2k(
    const float* __restrict__ xpT, float* __restrict__ out)
{
    const int kp = blockIdx.x;          // k0 = 2kp, k1 = 2kp+1
    const int ip = blockIdx.y;
    const int t  = threadIdx.x;
    const int lane = t & 63;
    const int w    = t >> 6;

    __shared__ float xs[BB][12];        // 24 KiB
    __shared__ float ps[8][128][2];     // 8 KiB

    // fill row j=t: fold 8 split partials for 10 (k,d) values, pre-scale.
    // Loads coalesced across t (512-wide rows of xpT).
    const int kb0 = kp * 10;            // = (2kp)*5
    #pragma unroll
    for (int c = 0; c < 10; ++c) {
        float v = 0.f;
        #pragma unroll
        for (int s = 0; s < SPLITS; ++s)
            v += xpT[((size_t)s * KDP + kb0 + c) * BB + t];
        xs[t][c] = LOG2E * v;
    }
    __syncthreads();

    // register-resident xi: 2 i-rows x 2 k x 5 d = 20 regs
    float xi[2][10];
    #pragma unroll
    for (int r = 0; r < 2; ++r) {
        const int i = ip * 128 + r * 64 + lane;
        #pragma unroll
        for (int c = 0; c < 10; ++c) xi[r][c] = xs[i][c];
    }

    float a00 = 0.f, a01 = 0.f, a10 = 0.f, a11 = 0.f;  // [r][kk]
    const int j0 = w << 6;
    #pragma unroll 2
    for (int jj = 0; jj < 64; ++jj) {
        const int j = j0 + jj;          // wave-uniform -> LDS broadcast
        float4 xjA = *(const float4*)&xs[j][0];   // k0 d0..d3
        float4 xjB = *(const float4*)&xs[j][4];   // k0 d4, k1 d0..d2
        float2 xjC = *(const float2*)&xs[j][8];   // k1 d3, d4
        {   // r = 0
            float aa = (fabsf(xi[0][0] - xjA.x) + fabsf(xi[0][1] - xjA.y))
                     + (fabsf(xi[0][2] - xjA.z) + fabsf(xi[0][3] - xjA.w))
                     + fabsf(xi[0][4] - xjB.x);
            float bb = (fabsf(xi[0][5] - xjB.y) + fabsf(xi[0][6] - xjB.z))
                     + (fabsf(xi[0][7] - xjB.w) + fabsf(xi[0][8] - xjC.x))
                     + fabsf(xi[0][9] - xjC.y);
            a00 += __builtin_amdgcn_exp2f(-aa);
            a01 += __builtin_amdgcn_exp2f(-bb);
        }
        {   // r = 1
            float aa = (fabsf(xi[1][0] - xjA.x) + fabsf(xi[1][1] - xjA.y))
                     + (fabsf(xi[1][2] - xjA.z) + fabsf(xi[1][3] - xjA.w))
                     + fabsf(xi[1][4] - xjB.x);
            float bb = (fabsf(xi[1][5] - xjB.y) + fabsf(xi[1][6] - xjB.z))
                     + (fabsf(xi[1][7] - xjB.w) + fabsf(xi[1][8] - xjC.x))
                     + fabsf(xi[1][9] - xjC.y);
            a10 += __builtin_amdgcn_exp2f(-aa);
            a11 += __builtin_amdgcn_exp2f(-bb);
        }
    }

    ps[w][lane][0]      = a00;
    ps[w][lane][1]      = a01;
    ps[w][lane + 64][0] = a10;
    ps[w][lane + 64][1] = a11;
    __syncthreads();

    // reduce 8 waves; t in [0,256): il = t>>1 (0..127), kk = t&1
    if (t < 256) {
        const int il = t >> 1;
        const int kk = t & 1;
        float v = 0.f;
        #pragma unroll
        for (int q = 0; q < 8; ++q) v += ps[q][il][kk];
        out[(size_t)(ip * 128 + il) * KK + kp * 2 + kk] = v;
    }
}

// ---------------- last-resort fallback (ws too small) ----------------
__global__ __launch_bounds__(1024, 1) void mbd_fused(
    const float* __restrict__ in, const float* __restrict__ T, float* __restrict__ out)
{
    const int k = blockIdx.x;
    const int t = threadIdx.x;
    const int i = t & (BB - 1);
    const int h = t >> 9;

    __shared__ float xk[1024][8];

    float a0 = 0.f, a1 = 0.f, a2 = 0.f, a3 = 0.f, a4 = 0.f;
    const float4* inrow = (const float4*)(in + (size_t)i * FF + (size_t)h * 512);
    const float* Tk = T + 5 * k + (size_t)h * 512 * KD;

    for (int ff = 0; ff < 512; ff += 4) {
        float4 v = inrow[ff >> 2];
        const float* tp = Tk + (size_t)ff * KD;
        a0 = fmaf(v.x, tp[0], a0); a1 = fmaf(v.x, tp[1], a1); a2 = fmaf(v.x, tp[2], a2);
        a3 = fmaf(v.x, tp[3], a3); a4 = fmaf(v.x, tp[4], a4); tp += KD;
        a0 = fmaf(v.y, tp[0], a0); a1 = fmaf(v.y, tp[1], a1); a2 = fmaf(v.y, tp[2], a2);
        a3 = fmaf(v.y, tp[3], a3); a4 = fmaf(v.y, tp[4], a4); tp += KD;
        a0 = fmaf(v.z, tp[0], a0); a1 = fmaf(v.z, tp[1], a1); a2 = fmaf(v.z, tp[2], a2);
        a3 = fmaf(v.z, tp[3], a3); a4 = fmaf(v.z, tp[4], a4); tp += KD;
        a0 = fmaf(v.w, tp[0], a0); a1 = fmaf(v.w, tp[1], a1); a2 = fmaf(v.w, tp[2], a2);
        a3 = fmaf(v.w, tp[3], a3); a4 = fmaf(v.w, tp[4], a4);
    }
    xk[t][0] = a0; xk[t][1] = a1; xk[t][2] = a2; xk[t][3] = a3; xk[t][4] = a4;
    __syncthreads();
    if (t < BB) {
        xk[t][0] += xk[t + BB][0]; xk[t][1] += xk[t + BB][1]; xk[t][2] += xk[t + BB][2];
        xk[t][3] += xk[t + BB][3]; xk[t][4] += xk[t + BB][4];
    }
    __syncthreads();

    const int jg = t >> 9;
    const float4 xiv = *(const float4*)&xk[i][0];
    const float xi4 = xk[i][4];
    float s0 = 0.f;
    const int j0 = jg << 8;
    for (int jj = 0; jj < 256; ++jj) {
        const int j = j0 + jj;
        float4 xj = *(const float4*)&xk[j][0];
        float xj4 = xk[j][4];
        float aa = (fabsf(xiv.x - xj.x) + fabsf(xiv.y - xj.y))
                 + (fabsf(xiv.z - xj.z) + fabsf(xiv.w - xj.w)) + fabsf(xi4 - xj4);
        s0 += __builtin_amdgcn_exp2f(-1.4426950408889634f * aa);
    }
    xk[BB + i][jg] = s0;
    __syncthreads();
    if (t < BB)
        out[(size_t)t * KK + k] = xk[BB + t][0] + xk[BB + t][1];
}

// ---------------- launch ----------------
extern "C" void kernel_launch(void* const* d_in, const int* in_sizes, int n_in,
                              void* d_out, int out_size, void* d_ws, size_t ws_size,
                              hipStream_t stream) {
    const float* in = (const float*)d_in[0];   // [512, 1024]
    const float* T  = (const float*)d_in[1];   // [1024, 500]
    float* out = (float*)d_out;                // [512, 100]

    const size_t xpT_bytes = (size_t)SPLITS * KDP * BB * sizeof(float);  // 8 MiB

    if (ws_size < xpT_bytes) {
        mbd_fused<<<KK, 1024, 0, stream>>>(in, T, out);
        return;
    }

    float* xpT = (float*)d_ws;

    kA<<<512, 256, 0, stream>>>(in, T, xpT);

    dim3 g2(KK / 2, 4);                // 50 x 4 = 200 blocks
    pair2k<<<g2, 512, 0, stream>>>(xpT, out);
}